// Round 9
// baseline (495.798 us; speedup 1.0000x reference)
//
#include <hip/hip_runtime.h>
#include <hip/hip_bf16.h>

typedef __attribute__((ext_vector_type(8))) short s16x8;
typedef __attribute__((ext_vector_type(4))) short s16x4;
typedef __attribute__((ext_vector_type(4))) float f32x4;
typedef __attribute__((ext_vector_type(4))) _Float16 f16x4;

// PV path: prefer bf16 16x16x16 MFMA (legacy "_1k" builtin name); if absent,
// fall back to the always-present f16 16x16x16 MFMA and store V as f16.
#if __has_builtin(__builtin_amdgcn_mfma_f32_16x16x16bf16_1k)
#define PV_USE_BF16 1
#else
#define PV_USE_BF16 0
#endif

#define S_LEN 2048
#define EMB   512
#define MROWS 8192   // S*B

__device__ __forceinline__ float bf2f(short x) {
    union { float f; unsigned u; } z; z.u = ((unsigned)(unsigned short)x) << 16; return z.f;
}
__device__ __forceinline__ short f2bf(float f) {
    union { float f; unsigned u; } z; z.f = f;
    unsigned r = z.u + 0x7FFF + ((z.u >> 16) & 1);   // round-to-nearest-even
    return (short)(r >> 16);
}
// storage format of V (bf16 normally; f16 when PV falls back to f16 MFMA)
__device__ __forceinline__ short f2v(float f) {
#if PV_USE_BF16
    return f2bf(f);
#else
    union { _Float16 h; short s; } u; u.h = (_Float16)f; return u.s;
#endif
}

// Load an 8-element chunk at element offset `off`, as bf16x8.
template<int F32>
__device__ __forceinline__ s16x8 load_chunk(const void* p, size_t off) {
    if (F32) {
        const float* f = (const float*)p + off;
        f32x4 lo = *(const f32x4*)f;
        f32x4 hi = *(const f32x4*)(f + 4);
        s16x8 r;
        r[0] = f2bf(lo[0]); r[1] = f2bf(lo[1]); r[2] = f2bf(lo[2]); r[3] = f2bf(lo[3]);
        r[4] = f2bf(hi[0]); r[5] = f2bf(hi[1]); r[6] = f2bf(hi[2]); r[7] = f2bf(hi[3]);
        return r;
    } else {
        return *(const s16x8*)((const short*)p + off);
    }
}

// ---------------------------------------------------------------------------
// BT-GEMM mainloop: C[128x128] += A[128xK] * B[128xK]^T
// ---------------------------------------------------------------------------
template<int AF32, int BF32>
__device__ __forceinline__ void gemm_mainloop(const void* __restrict__ Ag,
                                              const void* __restrict__ Bg,
                                              short* sA, short* sB,
                                              f32x4 acc[4][4], int K)
{
    const int tid  = threadIdx.x;
    const int lane = tid & 63;
    const int wv   = tid >> 6;
    const int l15  = lane & 15, quad = lane >> 4;
    const int wm   = (wv >> 1) * 64, wn = (wv & 1) * 64;

    const int r0 = tid >> 2,          kc0 = (tid & 3) * 8;
    const int r1 = (256 + tid) >> 2,  kc1 = ((256 + tid) & 3) * 8;

    for (int kt = 0; kt < K; kt += 32) {
        s16x8 a0 = load_chunk<AF32>(Ag, (size_t)r0 * K + kt + kc0);
        s16x8 b0 = load_chunk<BF32>(Bg, (size_t)r0 * K + kt + kc0);
        s16x8 a1 = load_chunk<AF32>(Ag, (size_t)r1 * K + kt + kc1);
        s16x8 b1 = load_chunk<BF32>(Bg, (size_t)r1 * K + kt + kc1);

        __syncthreads();
        *(s16x8*)(sA + tid * 8)         = a0;
        *(s16x8*)(sA + (256 + tid) * 8) = a1;
        *(s16x8*)(sB + tid * 8)         = b0;
        *(s16x8*)(sB + (256 + tid) * 8) = b1;
        __syncthreads();

        s16x8 aF[4], bF[4];
#pragma unroll
        for (int i = 0; i < 4; ++i)
            aF[i] = *(const s16x8*)(sA + (wm + i * 16 + l15) * 32 + quad * 8);
#pragma unroll
        for (int j = 0; j < 4; ++j)
            bF[j] = *(const s16x8*)(sB + (wn + j * 16 + l15) * 32 + quad * 8);

#pragma unroll
        for (int i = 0; i < 4; ++i)
#pragma unroll
            for (int j = 0; j < 4; ++j)
                acc[i][j] = __builtin_amdgcn_mfma_f32_16x16x32_bf16(aF[i], bF[j], acc[i][j], 0, 0, 0);
    }
}

// ---------------------------------------------------------------------------
// Kernel 1: fused QKV projection (fp32 in -> bf16 out; V in f2v format).
// ---------------------------------------------------------------------------
__global__ __launch_bounds__(256) void qkv_proj(const float* __restrict__ query,
                                                const float* __restrict__ key,
                                                const float* __restrict__ value,
                                                const float* __restrict__ W,
                                                const float* __restrict__ bias,
                                                short* __restrict__ q,
                                                short* __restrict__ k,
                                                short* __restrict__ v)
{
    __shared__ __align__(16) short sA[4096], sB[4096];
    const int z = blockIdx.z;
    const float* X  = (z == 0) ? query : (z == 1) ? key : value;
    const float* Wz = W    + (z == 2 ? (size_t)1024 * EMB : 0);
    const float* bz = bias + (z == 2 ? 1024 : 0);
    short* dst = (z == 0) ? q : (z == 1) ? k : v;
    const float scale = (z == 0) ? 0.125f : 1.0f;

    const int blockM = blockIdx.y * 128, blockN = blockIdx.x * 128;

    f32x4 acc[4][4];
#pragma unroll
    for (int i = 0; i < 4; ++i)
#pragma unroll
        for (int j = 0; j < 4; ++j)
            acc[i][j] = (f32x4){0.f, 0.f, 0.f, 0.f};

    gemm_mainloop<1, 1>(X + (size_t)blockM * EMB, Wz + (size_t)blockN * EMB,
                        sA, sB, acc, EMB);

    const int tid = threadIdx.x, lane = tid & 63, wv = tid >> 6;
    const int l15 = lane & 15, quad = lane >> 4;
    const int wm = (wv >> 1) * 64, wn = (wv & 1) * 64;

#pragma unroll
    for (int j = 0; j < 4; ++j) {
        int col = blockN + wn + j * 16 + l15;
        float bval = bz[col];
        int h = col >> 6, hd = col & 63;
#pragma unroll
        for (int i = 0; i < 4; ++i) {
#pragma unroll
            for (int r = 0; r < 4; ++r) {
                int row = blockM + wm + i * 16 + quad * 4 + r;
                int s = row >> 2, b = row & 3;
                float val = (acc[i][j][r] + bval) * scale;
                short bits = (z == 2) ? f2v(val) : f2bf(val);
                dst[((size_t)((b * 8 + h) * 2048 + s)) * 64 + hd] = bits;
            }
        }
    }
}

// ---------------------------------------------------------------------------
// Kernel 2: V transpose (BH,S,HD) -> (BH,HD,S). Dtype-agnostic (16-bit).
// ---------------------------------------------------------------------------
__global__ __launch_bounds__(256) void transpose_v(const short* __restrict__ v,
                                                   short* __restrict__ vt)
{
    __shared__ __align__(16) short t[64 * 68];
    const int bh = blockIdx.y, s0 = blockIdx.x * 64, tid = threadIdx.x;

#pragma unroll
    for (int p = 0; p < 2; ++p) {
        int r  = (tid >> 3) + p * 32;
        int cc = (tid & 7) * 8;
        s16x8 d = *(const s16x8*)(v + ((size_t)(bh * 2048 + s0 + r)) * 64 + cc);
        s16x4 lo = {d[0], d[1], d[2], d[3]};
        s16x4 hi = {d[4], d[5], d[6], d[7]};
        *(s16x4*)(t + r * 68 + cc)     = lo;
        *(s16x4*)(t + r * 68 + cc + 4) = hi;
    }
    __syncthreads();
#pragma unroll
    for (int p = 0; p < 2; ++p) {
        int hd = (tid >> 3) + p * 32;
        int so = (tid & 7) * 8;
        s16x8 d;
#pragma unroll
        for (int j = 0; j < 8; ++j) d[j] = t[(so + j) * 68 + hd];
        *(s16x8*)(vt + ((size_t)(bh * 64 + hd)) * 2048 + s0 + so) = d;
    }
}

// ---------------------------------------------------------------------------
// Kernel 3 (v4): flash attention — NO LDS in the loop.
// S^T = mfma(A=K, B=Q) -> C-layout D[key=quad*4+r][qrow=l15]; P^T = exp(S^T)
// is exactly the 16x16x16 A-fragment (A[m=l15][k=quad*4+j]) -> in-lane pack,
// zero cross-lane traffic. PV = 16 x mfma_f32_16x16x16 (bf16 or f16 per
// PV_USE_BF16) with V^T B-frags (8B loads). Output C-layout matches the
// old epilogue. Row sums: lane partials + xor16/32 butterfly at the end.
// XCD swizzle kept: bh = blockIdx.x.
// ---------------------------------------------------------------------------
__global__ __launch_bounds__(256, 4) void flash_attn(const short* __restrict__ q,
                                                     const short* __restrict__ k,
                                                     const short* __restrict__ vt,
                                                     short* __restrict__ attn)
{
    const int bh = blockIdx.x;            // fast grid dim -> XCD locality
    const int q0 = blockIdx.y * 64;
    const int tid = threadIdx.x, wv = tid >> 6, lane = tid & 63;
    const int l15 = lane & 15, quad = lane >> 4;

    const short* qp = q + ((size_t)(bh * 2048 + q0 + wv * 16 + l15)) * 64 + quad * 8;
    s16x8 qf0 = *(const s16x8*)qp;
    s16x8 qf1 = *(const s16x8*)(qp + 32);

    // K A-frag base: K[key=l15+16ct+kt][d=quad*8+j]
    const short* kl = k  + (size_t)bh * 2048 * 64 + (size_t)l15 * 64 + quad * 8;
    // V^T B-frag base (16x16x16): V^T[hd=l15+16nt][key=kt+16ct+quad*4+j]
    const short* vl = vt + (size_t)bh * 64 * 2048 + (size_t)l15 * 2048 + quad * 4;

#if PV_USE_BF16
    typedef s16x4 pvec;
#else
    typedef f16x4 pvec;
#endif

    f32x4 o[4];
    float lsum = 0.f;
#pragma unroll
    for (int i = 0; i < 4; ++i) o[i] = (f32x4){0.f, 0.f, 0.f, 0.f};

    for (int kt = 0; kt < 2048; kt += 64) {
        // ---- all global loads for this iteration ----
        s16x8 kf[4][2];
#pragma unroll
        for (int ct = 0; ct < 4; ++ct) {
            const short* kp = kl + (size_t)(kt + ct * 16) * 64;
            kf[ct][0] = *(const s16x8*)kp;
            kf[ct][1] = *(const s16x8*)(kp + 32);
        }
        pvec vf[4][4];   // [nt][ct]
#pragma unroll
        for (int nt = 0; nt < 4; ++nt)
#pragma unroll
            for (int ct = 0; ct < 4; ++ct)
                vf[nt][ct] = *(const pvec*)(vl + (size_t)(nt * 16) * 2048 + kt + ct * 16);

        // ---- S^T: mfma(A=K, B=Q) -> D[key=quad*4+r][qrow=l15] ----
        f32x4 sc[4];
#pragma unroll
        for (int ct = 0; ct < 4; ++ct) {
            f32x4 c = (f32x4){0.f, 0.f, 0.f, 0.f};
            c = __builtin_amdgcn_mfma_f32_16x16x32_bf16(kf[ct][0], qf0, c, 0, 0, 0);
            c = __builtin_amdgcn_mfma_f32_16x16x32_bf16(kf[ct][1], qf1, c, 0, 0, 0);
            sc[ct] = c;
        }
        // ---- P^T = exp(S^T); in-lane pack to 16x16x16 A-frags ----
        pvec pf[4];
#pragma unroll
        for (int ct = 0; ct < 4; ++ct)
#pragma unroll
            for (int r = 0; r < 4; ++r) {
                float p = __expf(sc[ct][r]);
                lsum += p;               // this lane's keys for qrow=l15
#if PV_USE_BF16
                pf[ct][r] = f2bf(p);
#else
                pf[ct][r] = (_Float16)p;
#endif
            }
        // ---- PV: O[qrow][hd] += P^T-frag x V^T-frag (16x16x16) ----
#pragma unroll
        for (int nt = 0; nt < 4; ++nt)
#pragma unroll
            for (int ct = 0; ct < 4; ++ct)
#if PV_USE_BF16
                o[nt] = __builtin_amdgcn_mfma_f32_16x16x16bf16_1k(pf[ct], vf[nt][ct], o[nt], 0, 0, 0);
#else
                o[nt] = __builtin_amdgcn_mfma_f32_16x16x16f16(pf[ct], vf[nt][ct], o[nt], 0, 0, 0);
#endif
    }

    // ---- row sums: lanes sharing l15 (across quads) hold one qrow ----
    float s = lsum;
    s += __shfl_xor(s, 16, 64);
    s += __shfl_xor(s, 32, 64);
    float sinv = 1.0f / s;               // valid in every lane, for qrow=l15
    // redistribute: output lane needs qrow=quad*4+r -> src lane l15'=quad*4+r
    float inv[4];
#pragma unroll
    for (int r = 0; r < 4; ++r)
        inv[r] = __shfl(sinv, quad * 20 + r, 64);

    // ---- epilogue: O / l, write to (S*B, E) ----
    const int b = bh >> 3, h = bh & 7;
#pragma unroll
    for (int r = 0; r < 4; ++r) {
        int srow = q0 + wv * 16 + quad * 4 + r;
#pragma unroll
        for (int nt = 0; nt < 4; ++nt)
            attn[(size_t)(srow * 4 + b) * 512 + h * 64 + nt * 16 + l15] = f2bf(o[nt][r] * inv[r]);
    }
}

// ---------------------------------------------------------------------------
// Kernel 4: output projection. A = attn (bf16 scratch), B = W (fp32), out FP32.
// ---------------------------------------------------------------------------
__global__ __launch_bounds__(256) void out_proj(const short* __restrict__ attn,
                                                const float* __restrict__ W,
                                                const float* __restrict__ bias,
                                                float* __restrict__ out)
{
    __shared__ __align__(16) short sA[4096], sB[4096];
    const int blockM = blockIdx.y * 128, blockN = blockIdx.x * 128;

    f32x4 acc[4][4];
#pragma unroll
    for (int i = 0; i < 4; ++i)
#pragma unroll
        for (int j = 0; j < 4; ++j)
            acc[i][j] = (f32x4){0.f, 0.f, 0.f, 0.f};

    gemm_mainloop<0, 1>(attn + (size_t)blockM * EMB, W + (size_t)blockN * EMB,
                        sA, sB, acc, EMB);

    const int tid = threadIdx.x, lane = tid & 63, wv = tid >> 6;
    const int l15 = lane & 15, quad = lane >> 4;
    const int wm = (wv >> 1) * 64, wn = (wv & 1) * 64;

#pragma unroll
    for (int j = 0; j < 4; ++j) {
        int col = blockN + wn + j * 16 + l15;
        float bval = bias[col];
#pragma unroll
        for (int i = 0; i < 4; ++i) {
#pragma unroll
            for (int r = 0; r < 4; ++r) {
                int row = blockM + wm + i * 16 + quad * 4 + r;
                out[(size_t)row * 512 + col] = acc[i][j][r] + bval;
            }
        }
    }
}

// ---------------------------------------------------------------------------
// Dtype contract: inputs FP32, output FP32. Internals bf16 (V possibly f16).
//   qkv_proj:    fp32 inputs -> bf16 q,k + f2v-format vbuf     [ws: 24 MB]
//   transpose_v: vbuf(v) -> d_out (V^T, first 8 MB of 16 MB fp32 buffer)
//   flash_attn:  q, k, d_out(V^T) -> vbuf (attn bf16; v dead)
//   out_proj:    vbuf(attn) + fp32 W_out -> d_out (fp32 final, overwrites V^T)
// ---------------------------------------------------------------------------
extern "C" void kernel_launch(void* const* d_in, const int* in_sizes, int n_in,
                              void* d_out, int out_size, void* d_ws, size_t ws_size,
                              hipStream_t stream)
{
    const float* query = (const float*)d_in[0];
    const float* key   = (const float*)d_in[1];
    const float* value = (const float*)d_in[2];
    const float* ipw   = (const float*)d_in[3];   // (1536, 512)
    const float* ipb   = (const float*)d_in[4];   // (1536,)
    const float* opw   = (const float*)d_in[5];   // (512, 512)
    const float* opb   = (const float*)d_in[6];   // (512,)
    float* out = (float*)d_out;

    const size_t NELEM = (size_t)MROWS * EMB;     // 4,194,304 elements
    short* q    = (short*)d_ws;
    short* k    = q + NELEM;
    short* vbuf = k + NELEM;                      // holds v, then attn
    short* vt   = (short*)d_out;                  // 16-bit scratch inside fp32 d_out

    qkv_proj   <<<dim3(4, 64, 3), 256, 0, stream>>>(query, key, value, ipw, ipb, q, k, vbuf);
    transpose_v<<<dim3(32, 32),   256, 0, stream>>>(vbuf, vt);
    // grid: x = bh (XCD-local), y = q-tile
    flash_attn <<<dim3(32, 32),   256, 0, stream>>>(q, k, vt, vbuf);
    out_proj   <<<dim3(4, 64),    256, 0, stream>>>(vbuf, opw, opb, out);
}

// Round 10
// 228.221 us; speedup vs baseline: 2.1724x; 2.1724x over previous
//
#include <hip/hip_runtime.h>
#include <hip/hip_bf16.h>

typedef __attribute__((ext_vector_type(8))) short s16x8;
typedef __attribute__((ext_vector_type(4))) short s16x4;
typedef __attribute__((ext_vector_type(4))) float f32x4;
typedef __attribute__((ext_vector_type(4))) _Float16 f16x4;

// PV path: prefer bf16 16x16x16 MFMA (legacy "_1k" builtin name); if absent,
// fall back to the always-present f16 16x16x16 MFMA and store V as f16.
#if __has_builtin(__builtin_amdgcn_mfma_f32_16x16x16bf16_1k)
#define PV_USE_BF16 1
#else
#define PV_USE_BF16 0
#endif

#define S_LEN 2048
#define EMB   512
#define MROWS 8192   // S*B

__device__ __forceinline__ float bf2f(short x) {
    union { float f; unsigned u; } z; z.u = ((unsigned)(unsigned short)x) << 16; return z.f;
}
__device__ __forceinline__ short f2bf(float f) {
    union { float f; unsigned u; } z; z.f = f;
    unsigned r = z.u + 0x7FFF + ((z.u >> 16) & 1);   // round-to-nearest-even
    return (short)(r >> 16);
}
// storage format of V (bf16 normally; f16 when PV falls back to f16 MFMA)
__device__ __forceinline__ short f2v(float f) {
#if PV_USE_BF16
    return f2bf(f);
#else
    union { _Float16 h; short s; } u; u.h = (_Float16)f; return u.s;
#endif
}

// Load an 8-element chunk at element offset `off`, as bf16x8.
template<int F32>
__device__ __forceinline__ s16x8 load_chunk(const void* p, size_t off) {
    if (F32) {
        const float* f = (const float*)p + off;
        f32x4 lo = *(const f32x4*)f;
        f32x4 hi = *(const f32x4*)(f + 4);
        s16x8 r;
        r[0] = f2bf(lo[0]); r[1] = f2bf(lo[1]); r[2] = f2bf(lo[2]); r[3] = f2bf(lo[3]);
        r[4] = f2bf(hi[0]); r[5] = f2bf(hi[1]); r[6] = f2bf(hi[2]); r[7] = f2bf(hi[3]);
        return r;
    } else {
        return *(const s16x8*)((const short*)p + off);
    }
}

// ---------------------------------------------------------------------------
// BT-GEMM mainloop: C[128x128] += A[128xK] * B[128xK]^T
// ---------------------------------------------------------------------------
template<int AF32, int BF32>
__device__ __forceinline__ void gemm_mainloop(const void* __restrict__ Ag,
                                              const void* __restrict__ Bg,
                                              short* sA, short* sB,
                                              f32x4 acc[4][4], int K)
{
    const int tid  = threadIdx.x;
    const int lane = tid & 63;
    const int wv   = tid >> 6;
    const int l15  = lane & 15, quad = lane >> 4;
    const int wm   = (wv >> 1) * 64, wn = (wv & 1) * 64;

    const int r0 = tid >> 2,          kc0 = (tid & 3) * 8;
    const int r1 = (256 + tid) >> 2,  kc1 = ((256 + tid) & 3) * 8;

    for (int kt = 0; kt < K; kt += 32) {
        s16x8 a0 = load_chunk<AF32>(Ag, (size_t)r0 * K + kt + kc0);
        s16x8 b0 = load_chunk<BF32>(Bg, (size_t)r0 * K + kt + kc0);
        s16x8 a1 = load_chunk<AF32>(Ag, (size_t)r1 * K + kt + kc1);
        s16x8 b1 = load_chunk<BF32>(Bg, (size_t)r1 * K + kt + kc1);

        __syncthreads();
        *(s16x8*)(sA + tid * 8)         = a0;
        *(s16x8*)(sA + (256 + tid) * 8) = a1;
        *(s16x8*)(sB + tid * 8)         = b0;
        *(s16x8*)(sB + (256 + tid) * 8) = b1;
        __syncthreads();

        s16x8 aF[4], bF[4];
#pragma unroll
        for (int i = 0; i < 4; ++i)
            aF[i] = *(const s16x8*)(sA + (wm + i * 16 + l15) * 32 + quad * 8);
#pragma unroll
        for (int j = 0; j < 4; ++j)
            bF[j] = *(const s16x8*)(sB + (wn + j * 16 + l15) * 32 + quad * 8);

#pragma unroll
        for (int i = 0; i < 4; ++i)
#pragma unroll
            for (int j = 0; j < 4; ++j)
                acc[i][j] = __builtin_amdgcn_mfma_f32_16x16x32_bf16(aF[i], bF[j], acc[i][j], 0, 0, 0);
    }
}

// ---------------------------------------------------------------------------
// Kernel 1: fused QKV projection (fp32 in -> bf16 out; V in f2v format).
// ---------------------------------------------------------------------------
__global__ __launch_bounds__(256) void qkv_proj(const float* __restrict__ query,
                                                const float* __restrict__ key,
                                                const float* __restrict__ value,
                                                const float* __restrict__ W,
                                                const float* __restrict__ bias,
                                                short* __restrict__ q,
                                                short* __restrict__ k,
                                                short* __restrict__ v)
{
    __shared__ __align__(16) short sA[4096], sB[4096];
    const int z = blockIdx.z;
    const float* X  = (z == 0) ? query : (z == 1) ? key : value;
    const float* Wz = W    + (z == 2 ? (size_t)1024 * EMB : 0);
    const float* bz = bias + (z == 2 ? 1024 : 0);
    short* dst = (z == 0) ? q : (z == 1) ? k : v;
    const float scale = (z == 0) ? 0.125f : 1.0f;

    const int blockM = blockIdx.y * 128, blockN = blockIdx.x * 128;

    f32x4 acc[4][4];
#pragma unroll
    for (int i = 0; i < 4; ++i)
#pragma unroll
        for (int j = 0; j < 4; ++j)
            acc[i][j] = (f32x4){0.f, 0.f, 0.f, 0.f};

    gemm_mainloop<1, 1>(X + (size_t)blockM * EMB, Wz + (size_t)blockN * EMB,
                        sA, sB, acc, EMB);

    const int tid = threadIdx.x, lane = tid & 63, wv = tid >> 6;
    const int l15 = lane & 15, quad = lane >> 4;
    const int wm = (wv >> 1) * 64, wn = (wv & 1) * 64;

#pragma unroll
    for (int j = 0; j < 4; ++j) {
        int col = blockN + wn + j * 16 + l15;
        float bval = bz[col];
        int h = col >> 6, hd = col & 63;
#pragma unroll
        for (int i = 0; i < 4; ++i) {
#pragma unroll
            for (int r = 0; r < 4; ++r) {
                int row = blockM + wm + i * 16 + quad * 4 + r;
                int s = row >> 2, b = row & 3;
                float val = (acc[i][j][r] + bval) * scale;
                short bits = (z == 2) ? f2v(val) : f2bf(val);
                dst[((size_t)((b * 8 + h) * 2048 + s)) * 64 + hd] = bits;
            }
        }
    }
}

// ---------------------------------------------------------------------------
// Kernel 2: V transpose (BH,S,HD) -> (BH,HD,S). Dtype-agnostic (16-bit).
// ---------------------------------------------------------------------------
__global__ __launch_bounds__(256) void transpose_v(const short* __restrict__ v,
                                                   short* __restrict__ vt)
{
    __shared__ __align__(16) short t[64 * 68];
    const int bh = blockIdx.y, s0 = blockIdx.x * 64, tid = threadIdx.x;

#pragma unroll
    for (int p = 0; p < 2; ++p) {
        int r  = (tid >> 3) + p * 32;
        int cc = (tid & 7) * 8;
        s16x8 d = *(const s16x8*)(v + ((size_t)(bh * 2048 + s0 + r)) * 64 + cc);
        s16x4 lo = {d[0], d[1], d[2], d[3]};
        s16x4 hi = {d[4], d[5], d[6], d[7]};
        *(s16x4*)(t + r * 68 + cc)     = lo;
        *(s16x4*)(t + r * 68 + cc + 4) = hi;
    }
    __syncthreads();
#pragma unroll
    for (int p = 0; p < 2; ++p) {
        int hd = (tid >> 3) + p * 32;
        int so = (tid & 7) * 8;
        s16x8 d;
#pragma unroll
        for (int j = 0; j < 8; ++j) d[j] = t[(so + j) * 68 + hd];
        *(s16x8*)(vt + ((size_t)(bh * 64 + hd)) * 2048 + s0 + so) = d;
    }
}

// ---------------------------------------------------------------------------
// Kernel 3 (v5): flash attention — cooperative LDS staging + in-register P.
// Round-9 lesson: per-wave K/V loads were 4x redundant (all waves load the
// same tile) and scatter-shaped (16 transactions/instr) -> ~2 GB from L2 +
// compiler load-sinking (VGPR=40) serialized everything at ~250-350 us.
// v5: m97-style two-barrier K-loop. 256 threads stage the 8 KB K-tile +
// 8 KB V^T-tile with coalesced 16B loads (4/thread) into padded LDS
// (72-short rows: 144 B = 9x16 B -> b128-aligned; bank stride 36==4 mod 32
// -> ~2-way = free). Next tile's global loads issue BEFORE computing the
// current tile (latency hidden behind MFMA+exp). Kept from round 9:
// S^T = mfma(A=K,B=Q); P^T = exp in 16x16x16 A-frag layout (in-lane pack,
// zero cross-lane traffic); PV via 16x16x16 MFMA; end-of-loop row-sum
// butterfly; XCD swizzle (bh = blockIdx.x).
// ---------------------------------------------------------------------------
__global__ __launch_bounds__(256, 4) void flash_attn(const short* __restrict__ q,
                                                     const short* __restrict__ k,
                                                     const short* __restrict__ vt,
                                                     short* __restrict__ attn)
{
    __shared__ __align__(16) short sK[64 * 72];   // [key][hd]
    __shared__ __align__(16) short sV[64 * 72];   // [hd][key]
    const int bh = blockIdx.x;            // fast grid dim -> XCD locality
    const int q0 = blockIdx.y * 64;
    const int tid = threadIdx.x, wv = tid >> 6, lane = tid & 63;
    const int l15 = lane & 15, quad = lane >> 4;

    const short* qp = q + ((size_t)(bh * 2048 + q0 + wv * 16 + l15)) * 64 + quad * 8;
    s16x8 qf0 = *(const s16x8*)qp;
    s16x8 qf1 = *(const s16x8*)(qp + 32);

    const short* kg = k  + (size_t)bh * 2048 * 64;   // + (kt+key)*64 + hd
    const short* vg = vt + (size_t)bh * 64 * 2048;   // + hd*2048 + kt + key

    // staging decomposition: chunk c in [0,512): row c>>3, col (c&7)*8
    const int r0 = tid >> 3,          c0 = (tid & 7) * 8;
    const int r1 = (tid + 256) >> 3,  c1 = ((tid + 256) & 7) * 8;

#if PV_USE_BF16
    typedef s16x4 pvec;
#else
    typedef f16x4 pvec;
#endif

    f32x4 o[4];
    float lsum = 0.f;
#pragma unroll
    for (int i = 0; i < 4; ++i) o[i] = (f32x4){0.f, 0.f, 0.f, 0.f};

    // ---- prologue: stage tile 0 ----
    s16x8 ka = *(const s16x8*)(kg + (size_t)r0 * 64 + c0);
    s16x8 kb = *(const s16x8*)(kg + (size_t)r1 * 64 + c1);
    s16x8 va = *(const s16x8*)(vg + (size_t)r0 * 2048 + c0);
    s16x8 vb = *(const s16x8*)(vg + (size_t)r1 * 2048 + c1);
    *(s16x8*)(sK + r0 * 72 + c0) = ka;
    *(s16x8*)(sK + r1 * 72 + c1) = kb;
    *(s16x8*)(sV + r0 * 72 + c0) = va;
    *(s16x8*)(sV + r1 * 72 + c1) = vb;
    __syncthreads();

    for (int kt = 0; kt < 2048; kt += 64) {
        // ---- issue next tile's global loads (latency hidden by compute) ----
        const int ktn = (kt + 64) & 2047;   // wraps on last iter (harmless)
        ka = *(const s16x8*)(kg + (size_t)(ktn + r0) * 64 + c0);
        kb = *(const s16x8*)(kg + (size_t)(ktn + r1) * 64 + c1);
        va = *(const s16x8*)(vg + (size_t)r0 * 2048 + ktn + c0);
        vb = *(const s16x8*)(vg + (size_t)r1 * 2048 + ktn + c1);

        // ---- S^T: mfma(A=K, B=Q) -> D[key=quad*4+r][qrow=l15] ----
        f32x4 sc[4];
#pragma unroll
        for (int ct = 0; ct < 4; ++ct) {
            s16x8 kf0 = *(const s16x8*)(sK + (ct * 16 + l15) * 72 + quad * 8);
            s16x8 kf1 = *(const s16x8*)(sK + (ct * 16 + l15) * 72 + quad * 8 + 32);
            f32x4 c = (f32x4){0.f, 0.f, 0.f, 0.f};
            c = __builtin_amdgcn_mfma_f32_16x16x32_bf16(kf0, qf0, c, 0, 0, 0);
            c = __builtin_amdgcn_mfma_f32_16x16x32_bf16(kf1, qf1, c, 0, 0, 0);
            sc[ct] = c;
        }
        // ---- P^T = exp(S^T); in-lane pack to 16x16x16 A-frags ----
        pvec pf[4];
#pragma unroll
        for (int ct = 0; ct < 4; ++ct)
#pragma unroll
            for (int r = 0; r < 4; ++r) {
                float p = __expf(sc[ct][r]);
                lsum += p;               // this lane's keys for qrow=l15
#if PV_USE_BF16
                pf[ct][r] = f2bf(p);
#else
                pf[ct][r] = (_Float16)p;
#endif
            }
        // ---- PV: O[qrow][hd] += P^T-frag x V^T-frag (16x16x16) ----
#pragma unroll
        for (int nt = 0; nt < 4; ++nt)
#pragma unroll
            for (int ct = 0; ct < 4; ++ct) {
                pvec vf = *(const pvec*)(sV + (nt * 16 + l15) * 72 + ct * 16 + quad * 4);
#if PV_USE_BF16
                o[nt] = __builtin_amdgcn_mfma_f32_16x16x16bf16_1k(pf[ct], vf, o[nt], 0, 0, 0);
#else
                o[nt] = __builtin_amdgcn_mfma_f32_16x16x16f16(pf[ct], vf, o[nt], 0, 0, 0);
#endif
            }
        // ---- rotate tile: all waves done reading, then overwrite ----
        __syncthreads();
        *(s16x8*)(sK + r0 * 72 + c0) = ka;
        *(s16x8*)(sK + r1 * 72 + c1) = kb;
        *(s16x8*)(sV + r0 * 72 + c0) = va;
        *(s16x8*)(sV + r1 * 72 + c1) = vb;
        __syncthreads();
    }

    // ---- row sums: lanes sharing l15 (across quads) hold one qrow ----
    float s = lsum;
    s += __shfl_xor(s, 16, 64);
    s += __shfl_xor(s, 32, 64);
    float sinv = 1.0f / s;               // valid in every lane, for qrow=l15
    float inv[4];
#pragma unroll
    for (int r = 0; r < 4; ++r)
        inv[r] = __shfl(sinv, quad * 20 + r, 64);

    // ---- epilogue: O / l, write to (S*B, E) ----
    const int b = bh >> 3, h = bh & 7;
#pragma unroll
    for (int r = 0; r < 4; ++r) {
        int srow = q0 + wv * 16 + quad * 4 + r;
#pragma unroll
        for (int nt = 0; nt < 4; ++nt)
            attn[(size_t)(srow * 4 + b) * 512 + h * 64 + nt * 16 + l15] = f2bf(o[nt][r] * inv[r]);
    }
}

// ---------------------------------------------------------------------------
// Kernel 4: output projection. A = attn (bf16 scratch), B = W (fp32), out FP32.
// ---------------------------------------------------------------------------
__global__ __launch_bounds__(256) void out_proj(const short* __restrict__ attn,
                                                const float* __restrict__ W,
                                                const float* __restrict__ bias,
                                                float* __restrict__ out)
{
    __shared__ __align__(16) short sA[4096], sB[4096];
    const int blockM = blockIdx.y * 128, blockN = blockIdx.x * 128;

    f32x4 acc[4][4];
#pragma unroll
    for (int i = 0; i < 4; ++i)
#pragma unroll
        for (int j = 0; j < 4; ++j)
            acc[i][j] = (f32x4){0.f, 0.f, 0.f, 0.f};

    gemm_mainloop<0, 1>(attn + (size_t)blockM * EMB, W + (size_t)blockN * EMB,
                        sA, sB, acc, EMB);

    const int tid = threadIdx.x, lane = tid & 63, wv = tid >> 6;
    const int l15 = lane & 15, quad = lane >> 4;
    const int wm = (wv >> 1) * 64, wn = (wv & 1) * 64;

#pragma unroll
    for (int j = 0; j < 4; ++j) {
        int col = blockN + wn + j * 16 + l15;
        float bval = bias[col];
#pragma unroll
        for (int i = 0; i < 4; ++i) {
#pragma unroll
            for (int r = 0; r < 4; ++r) {
                int row = blockM + wm + i * 16 + quad * 4 + r;
                out[(size_t)row * 512 + col] = acc[i][j][r] + bval;
            }
        }
    }
}

// ---------------------------------------------------------------------------
// Dtype contract: inputs FP32, output FP32. Internals bf16 (V possibly f16).
//   qkv_proj:    fp32 inputs -> bf16 q,k + f2v-format vbuf     [ws: 24 MB]
//   transpose_v: vbuf(v) -> d_out (V^T, first 8 MB of 16 MB fp32 buffer)
//   flash_attn:  q, k, d_out(V^T) -> vbuf (attn bf16; v dead)
//   out_proj:    vbuf(attn) + fp32 W_out -> d_out (fp32 final, overwrites V^T)
// ---------------------------------------------------------------------------
extern "C" void kernel_launch(void* const* d_in, const int* in_sizes, int n_in,
                              void* d_out, int out_size, void* d_ws, size_t ws_size,
                              hipStream_t stream)
{
    const float* query = (const float*)d_in[0];
    const float* key   = (const float*)d_in[1];
    const float* value = (const float*)d_in[2];
    const float* ipw   = (const float*)d_in[3];   // (1536, 512)
    const float* ipb   = (const float*)d_in[4];   // (1536,)
    const float* opw   = (const float*)d_in[5];   // (512, 512)
    const float* opb   = (const float*)d_in[6];   // (512,)
    float* out = (float*)d_out;

    const size_t NELEM = (size_t)MROWS * EMB;     // 4,194,304 elements
    short* q    = (short*)d_ws;
    short* k    = q + NELEM;
    short* vbuf = k + NELEM;                      // holds v, then attn
    short* vt   = (short*)d_out;                  // 16-bit scratch inside fp32 d_out

    qkv_proj   <<<dim3(4, 64, 3), 256, 0, stream>>>(query, key, value, ipw, ipb, q, k, vbuf);
    transpose_v<<<dim3(32, 32),   256, 0, stream>>>(vbuf, vt);
    // grid: x = bh (XCD-local), y = q-tile
    flash_attn <<<dim3(32, 32),   256, 0, stream>>>(q, k, vt, vbuf);
    out_proj   <<<dim3(4, 64),    256, 0, stream>>>(vbuf, opw, opb, out);
}

// Round 11
// 213.121 us; speedup vs baseline: 2.3264x; 1.0709x over previous
//
#include <hip/hip_runtime.h>
#include <hip/hip_bf16.h>

typedef __attribute__((ext_vector_type(8))) short s16x8;
typedef __attribute__((ext_vector_type(4))) short s16x4;
typedef __attribute__((ext_vector_type(4))) float f32x4;
typedef __attribute__((ext_vector_type(4))) _Float16 f16x4;

#if __has_builtin(__builtin_amdgcn_mfma_f32_16x16x16bf16_1k)
#define PV_USE_BF16 1
#else
#define PV_USE_BF16 0
#endif

#define S_LEN 2048
#define EMB   512
#define MROWS 8192   // S*B

__device__ __forceinline__ float bf2f(short x) {
    union { float f; unsigned u; } z; z.u = ((unsigned)(unsigned short)x) << 16; return z.f;
}
// RNE — used only in epilogues (few converts)
__device__ __forceinline__ short f2bf(float f) {
    union { float f; unsigned u; } z; z.f = f;
    unsigned r = z.u + 0x7FFF + ((z.u >> 16) & 1);
    return (short)(r >> 16);
}
// fast round-half-away (2 VALU ops) — staging/P-pack hot paths
__device__ __forceinline__ short f2bf_fast(float f) {
    union { float f; unsigned u; } z; z.f = f;
    return (short)((z.u + 0x8000u) >> 16);
}
// storage format of V (bf16 normally; f16 when PV falls back to f16 MFMA)
__device__ __forceinline__ short f2v(float f) {
#if PV_USE_BF16
    return f2bf(f);
#else
    union { _Float16 h; short s; } u; u.h = (_Float16)f; return u.s;
#endif
}

// ---------------------------------------------------------------------------
// BT-GEMM mainloop v2: C[128x128] += A[128xK] * B[128xK]^T — SOFTWARE
// PIPELINED (flash-v5 structure): prologue stages tile 0; each iteration
// issues next-tile global loads BEFORE computing the current tile from LDS,
// hiding L2/HBM latency behind 16 MFMAs. fp32 sources staged as 4 contiguous
// f32x4 per thread (fully coalesced) and converted with 2-op f2bf_fast.
// ---------------------------------------------------------------------------
template<int AF32, int BF32>
__device__ __forceinline__ void gemm_mainloop(const void* __restrict__ Ag,
                                              const void* __restrict__ Bg,
                                              short* sA, short* sB,
                                              f32x4 acc[4][4], int K)
{
    const int tid  = threadIdx.x;
    const int lane = tid & 63;
    const int wv   = tid >> 6;
    const int l15  = lane & 15, quad = lane >> 4;
    const int wm   = (wv >> 1) * 64, wn = (wv & 1) * 64;

    f32x4 afr[4], bfr[4];   // fp32 staging regs
    s16x8 ahr[2], bhr[2];   // bf16 staging regs

    auto loadT = [&](const void* G, int kt, f32x4* fr, s16x8* hr, int F32) {
        if (F32) {
#pragma unroll
            for (int p = 0; p < 4; ++p) {
                int c = tid + p * 256;     // 1024 chunks of 4 floats
                fr[p] = *(const f32x4*)((const float*)G + (size_t)(c >> 3) * K + kt + (c & 7) * 4);
            }
        } else {
#pragma unroll
            for (int p = 0; p < 2; ++p) {
                int c = tid + p * 256;     // 512 chunks of 8 shorts
                hr[p] = *(const s16x8*)((const short*)G + (size_t)(c >> 2) * K + kt + (c & 3) * 8);
            }
        }
    };
    auto commitT = [&](short* s, f32x4* fr, s16x8* hr, int F32) {
        if (F32) {
#pragma unroll
            for (int p = 0; p < 4; ++p) {
                int c = tid + p * 256;
                s16x4 o4;
                o4[0] = f2bf_fast(fr[p][0]); o4[1] = f2bf_fast(fr[p][1]);
                o4[2] = f2bf_fast(fr[p][2]); o4[3] = f2bf_fast(fr[p][3]);
                *(s16x4*)(s + c * 4) = o4;   // short idx row*32+col = c*4
            }
        } else {
#pragma unroll
            for (int p = 0; p < 2; ++p) {
                int c = tid + p * 256;
                *(s16x8*)(s + c * 8) = hr[p];
            }
        }
    };

    // prologue: stage tile 0
    loadT(Ag, 0, afr, ahr, AF32);
    loadT(Bg, 0, bfr, bhr, BF32);
    commitT(sA, afr, ahr, AF32);
    commitT(sB, bfr, bhr, BF32);
    __syncthreads();

    for (int kt = 0; kt < K; kt += 32) {
        // issue next tile's loads (wrapped on last iter — harmless)
        const int ktn = (kt + 32 < K) ? kt + 32 : 0;
        loadT(Ag, ktn, afr, ahr, AF32);
        loadT(Bg, ktn, bfr, bhr, BF32);

        // compute current tile from LDS
        s16x8 aF[4], bF[4];
#pragma unroll
        for (int i = 0; i < 4; ++i)
            aF[i] = *(const s16x8*)(sA + (wm + i * 16 + l15) * 32 + quad * 8);
#pragma unroll
        for (int j = 0; j < 4; ++j)
            bF[j] = *(const s16x8*)(sB + (wn + j * 16 + l15) * 32 + quad * 8);
#pragma unroll
        for (int i = 0; i < 4; ++i)
#pragma unroll
            for (int j = 0; j < 4; ++j)
                acc[i][j] = __builtin_amdgcn_mfma_f32_16x16x32_bf16(aF[i], bF[j], acc[i][j], 0, 0, 0);

        __syncthreads();    // all waves done reading
        commitT(sA, afr, ahr, AF32);
        commitT(sB, bfr, bhr, BF32);
        __syncthreads();    // next tile visible
    }
}

// ---------------------------------------------------------------------------
// Kernel 1: fused QKV projection (fp32 in -> bf16 out; V in f2v format).
// ---------------------------------------------------------------------------
__global__ __launch_bounds__(256, 3) void qkv_proj(const float* __restrict__ query,
                                                   const float* __restrict__ key,
                                                   const float* __restrict__ value,
                                                   const float* __restrict__ W,
                                                   const float* __restrict__ bias,
                                                   short* __restrict__ q,
                                                   short* __restrict__ k,
                                                   short* __restrict__ v)
{
    __shared__ __align__(16) short sA[4096], sB[4096];
    const int z = blockIdx.z;
    const float* X  = (z == 0) ? query : (z == 1) ? key : value;
    const float* Wz = W    + (z == 2 ? (size_t)1024 * EMB : 0);
    const float* bz = bias + (z == 2 ? 1024 : 0);
    short* dst = (z == 0) ? q : (z == 1) ? k : v;
    const float scale = (z == 0) ? 0.125f : 1.0f;

    const int blockM = blockIdx.y * 128, blockN = blockIdx.x * 128;

    f32x4 acc[4][4];
#pragma unroll
    for (int i = 0; i < 4; ++i)
#pragma unroll
        for (int j = 0; j < 4; ++j)
            acc[i][j] = (f32x4){0.f, 0.f, 0.f, 0.f};

    gemm_mainloop<1, 1>(X + (size_t)blockM * EMB, Wz + (size_t)blockN * EMB,
                        sA, sB, acc, EMB);

    const int tid = threadIdx.x, lane = tid & 63, wv = tid >> 6;
    const int l15 = lane & 15, quad = lane >> 4;
    const int wm = (wv >> 1) * 64, wn = (wv & 1) * 64;

#pragma unroll
    for (int j = 0; j < 4; ++j) {
        int col = blockN + wn + j * 16 + l15;
        float bval = bz[col];
        int h = col >> 6, hd = col & 63;
#pragma unroll
        for (int i = 0; i < 4; ++i) {
#pragma unroll
            for (int r = 0; r < 4; ++r) {
                int row = blockM + wm + i * 16 + quad * 4 + r;
                int s = row >> 2, b = row & 3;
                float val = (acc[i][j][r] + bval) * scale;
                short bits = (z == 2) ? f2v(val) : f2bf(val);
                dst[((size_t)((b * 8 + h) * 2048 + s)) * 64 + hd] = bits;
            }
        }
    }
}

// ---------------------------------------------------------------------------
// Kernel 2: V transpose (BH,S,HD) -> (BH,HD,S). Dtype-agnostic (16-bit).
// ---------------------------------------------------------------------------
__global__ __launch_bounds__(256) void transpose_v(const short* __restrict__ v,
                                                   short* __restrict__ vt)
{
    __shared__ __align__(16) short t[64 * 68];
    const int bh = blockIdx.y, s0 = blockIdx.x * 64, tid = threadIdx.x;

#pragma unroll
    for (int p = 0; p < 2; ++p) {
        int r  = (tid >> 3) + p * 32;
        int cc = (tid & 7) * 8;
        s16x8 d = *(const s16x8*)(v + ((size_t)(bh * 2048 + s0 + r)) * 64 + cc);
        s16x4 lo = {d[0], d[1], d[2], d[3]};
        s16x4 hi = {d[4], d[5], d[6], d[7]};
        *(s16x4*)(t + r * 68 + cc)     = lo;
        *(s16x4*)(t + r * 68 + cc + 4) = hi;
    }
    __syncthreads();
#pragma unroll
    for (int p = 0; p < 2; ++p) {
        int hd = (tid >> 3) + p * 32;
        int so = (tid & 7) * 8;
        s16x8 d;
#pragma unroll
        for (int j = 0; j < 8; ++j) d[j] = t[(so + j) * 68 + hd];
        *(s16x8*)(vt + ((size_t)(bh * 64 + hd)) * 2048 + s0 + so) = d;
    }
}

// ---------------------------------------------------------------------------
// Kernel 3 (v5.1): flash attention — cooperative LDS staging + in-register P.
// Same structure as round 10 (72.7 us); only change: f2bf_fast for P packing
// (the 16 RNE converts/iter were ~40% of the loop's VALU).
// ---------------------------------------------------------------------------
__global__ __launch_bounds__(256, 4) void flash_attn(const short* __restrict__ q,
                                                     const short* __restrict__ k,
                                                     const short* __restrict__ vt,
                                                     short* __restrict__ attn)
{
    __shared__ __align__(16) short sK[64 * 72];   // [key][hd]
    __shared__ __align__(16) short sV[64 * 72];   // [hd][key]
    const int bh = blockIdx.x;            // fast grid dim -> XCD locality
    const int q0 = blockIdx.y * 64;
    const int tid = threadIdx.x, wv = tid >> 6, lane = tid & 63;
    const int l15 = lane & 15, quad = lane >> 4;

    const short* qp = q + ((size_t)(bh * 2048 + q0 + wv * 16 + l15)) * 64 + quad * 8;
    s16x8 qf0 = *(const s16x8*)qp;
    s16x8 qf1 = *(const s16x8*)(qp + 32);

    const short* kg = k  + (size_t)bh * 2048 * 64;   // + (kt+key)*64 + hd
    const short* vg = vt + (size_t)bh * 64 * 2048;   // + hd*2048 + kt + key

    const int r0 = tid >> 3,          c0 = (tid & 7) * 8;
    const int r1 = (tid + 256) >> 3,  c1 = ((tid + 256) & 7) * 8;

#if PV_USE_BF16
    typedef s16x4 pvec;
#else
    typedef f16x4 pvec;
#endif

    f32x4 o[4];
    float lsum = 0.f;
#pragma unroll
    for (int i = 0; i < 4; ++i) o[i] = (f32x4){0.f, 0.f, 0.f, 0.f};

    // ---- prologue: stage tile 0 ----
    s16x8 ka = *(const s16x8*)(kg + (size_t)r0 * 64 + c0);
    s16x8 kb = *(const s16x8*)(kg + (size_t)r1 * 64 + c1);
    s16x8 va = *(const s16x8*)(vg + (size_t)r0 * 2048 + c0);
    s16x8 vb = *(const s16x8*)(vg + (size_t)r1 * 2048 + c1);
    *(s16x8*)(sK + r0 * 72 + c0) = ka;
    *(s16x8*)(sK + r1 * 72 + c1) = kb;
    *(s16x8*)(sV + r0 * 72 + c0) = va;
    *(s16x8*)(sV + r1 * 72 + c1) = vb;
    __syncthreads();

    for (int kt = 0; kt < 2048; kt += 64) {
        const int ktn = (kt + 64) & 2047;   // wraps on last iter (harmless)
        ka = *(const s16x8*)(kg + (size_t)(ktn + r0) * 64 + c0);
        kb = *(const s16x8*)(kg + (size_t)(ktn + r1) * 64 + c1);
        va = *(const s16x8*)(vg + (size_t)r0 * 2048 + ktn + c0);
        vb = *(const s16x8*)(vg + (size_t)r1 * 2048 + ktn + c1);

        // ---- S^T: mfma(A=K, B=Q) -> D[key=quad*4+r][qrow=l15] ----
        f32x4 sc[4];
#pragma unroll
        for (int ct = 0; ct < 4; ++ct) {
            s16x8 kf0 = *(const s16x8*)(sK + (ct * 16 + l15) * 72 + quad * 8);
            s16x8 kf1 = *(const s16x8*)(sK + (ct * 16 + l15) * 72 + quad * 8 + 32);
            f32x4 c = (f32x4){0.f, 0.f, 0.f, 0.f};
            c = __builtin_amdgcn_mfma_f32_16x16x32_bf16(kf0, qf0, c, 0, 0, 0);
            c = __builtin_amdgcn_mfma_f32_16x16x32_bf16(kf1, qf1, c, 0, 0, 0);
            sc[ct] = c;
        }
        // ---- P^T = exp(S^T); in-lane pack (fast cvt) ----
        pvec pf[4];
#pragma unroll
        for (int ct = 0; ct < 4; ++ct)
#pragma unroll
            for (int r = 0; r < 4; ++r) {
                float p = __expf(sc[ct][r]);
                lsum += p;
#if PV_USE_BF16
                pf[ct][r] = f2bf_fast(p);
#else
                pf[ct][r] = (_Float16)p;
#endif
            }
        // ---- PV: O[qrow][hd] += P^T-frag x V^T-frag (16x16x16) ----
#pragma unroll
        for (int nt = 0; nt < 4; ++nt)
#pragma unroll
            for (int ct = 0; ct < 4; ++ct) {
                pvec vf = *(const pvec*)(sV + (nt * 16 + l15) * 72 + ct * 16 + quad * 4);
#if PV_USE_BF16
                o[nt] = __builtin_amdgcn_mfma_f32_16x16x16bf16_1k(pf[ct], vf, o[nt], 0, 0, 0);
#else
                o[nt] = __builtin_amdgcn_mfma_f32_16x16x16f16(pf[ct], vf, o[nt], 0, 0, 0);
#endif
            }
        // ---- rotate tile ----
        __syncthreads();
        *(s16x8*)(sK + r0 * 72 + c0) = ka;
        *(s16x8*)(sK + r1 * 72 + c1) = kb;
        *(s16x8*)(sV + r0 * 72 + c0) = va;
        *(s16x8*)(sV + r1 * 72 + c1) = vb;
        __syncthreads();
    }

    // ---- row sums ----
    float s = lsum;
    s += __shfl_xor(s, 16, 64);
    s += __shfl_xor(s, 32, 64);
    float sinv = 1.0f / s;
    float inv[4];
#pragma unroll
    for (int r = 0; r < 4; ++r)
        inv[r] = __shfl(sinv, quad * 20 + r, 64);

    // ---- epilogue ----
    const int b = bh >> 3, h = bh & 7;
#pragma unroll
    for (int r = 0; r < 4; ++r) {
        int srow = q0 + wv * 16 + quad * 4 + r;
#pragma unroll
        for (int nt = 0; nt < 4; ++nt)
            attn[(size_t)(srow * 4 + b) * 512 + h * 64 + nt * 16 + l15] = f2bf(o[nt][r] * inv[r]);
    }
}

// ---------------------------------------------------------------------------
// Kernel 4: output projection. A = attn (bf16 scratch), B = W (fp32), out FP32.
// ---------------------------------------------------------------------------
__global__ __launch_bounds__(256, 3) void out_proj(const short* __restrict__ attn,
                                                   const float* __restrict__ W,
                                                   const float* __restrict__ bias,
                                                   float* __restrict__ out)
{
    __shared__ __align__(16) short sA[4096], sB[4096];
    const int blockM = blockIdx.y * 128, blockN = blockIdx.x * 128;

    f32x4 acc[4][4];
#pragma unroll
    for (int i = 0; i < 4; ++i)
#pragma unroll
        for (int j = 0; j < 4; ++j)
            acc[i][j] = (f32x4){0.f, 0.f, 0.f, 0.f};

    gemm_mainloop<0, 1>(attn + (size_t)blockM * EMB, W + (size_t)blockN * EMB,
                        sA, sB, acc, EMB);

    const int tid = threadIdx.x, lane = tid & 63, wv = tid >> 6;
    const int l15 = lane & 15, quad = lane >> 4;
    const int wm = (wv >> 1) * 64, wn = (wv & 1) * 64;

#pragma unroll
    for (int j = 0; j < 4; ++j) {
        int col = blockN + wn + j * 16 + l15;
        float bval = bias[col];
#pragma unroll
        for (int i = 0; i < 4; ++i) {
#pragma unroll
            for (int r = 0; r < 4; ++r) {
                int row = blockM + wm + i * 16 + quad * 4 + r;
                out[(size_t)row * 512 + col] = acc[i][j][r] + bval;
            }
        }
    }
}

// ---------------------------------------------------------------------------
// Dtype contract: inputs FP32, output FP32. Internals bf16 (V possibly f16).
//   qkv_proj:    fp32 inputs -> bf16 q,k + f2v-format vbuf     [ws: 24 MB]
//   transpose_v: vbuf(v) -> d_out (V^T, first 8 MB of 16 MB fp32 buffer)
//   flash_attn:  q, k, d_out(V^T) -> vbuf (attn bf16; v dead)
//   out_proj:    vbuf(attn) + fp32 W_out -> d_out (fp32 final, overwrites V^T)
// ---------------------------------------------------------------------------
extern "C" void kernel_launch(void* const* d_in, const int* in_sizes, int n_in,
                              void* d_out, int out_size, void* d_ws, size_t ws_size,
                              hipStream_t stream)
{
    const float* query = (const float*)d_in[0];
    const float* key   = (const float*)d_in[1];
    const float* value = (const float*)d_in[2];
    const float* ipw   = (const float*)d_in[3];   // (1536, 512)
    const float* ipb   = (const float*)d_in[4];   // (1536,)
    const float* opw   = (const float*)d_in[5];   // (512, 512)
    const float* opb   = (const float*)d_in[6];   // (512,)
    float* out = (float*)d_out;

    const size_t NELEM = (size_t)MROWS * EMB;     // 4,194,304 elements
    short* q    = (short*)d_ws;
    short* k    = q + NELEM;
    short* vbuf = k + NELEM;                      // holds v, then attn
    short* vt   = (short*)d_out;                  // 16-bit scratch inside fp32 d_out

    qkv_proj   <<<dim3(4, 64, 3), 256, 0, stream>>>(query, key, value, ipw, ipb, q, k, vbuf);
    transpose_v<<<dim3(32, 32),   256, 0, stream>>>(vbuf, vt);
    // grid: x = bh (XCD-local), y = q-tile
    flash_attn <<<dim3(32, 32),   256, 0, stream>>>(q, k, vt, vbuf);
    out_proj   <<<dim3(4, 64),    256, 0, stream>>>(vbuf, opw, opb, out);
}

// Round 12
// 212.133 us; speedup vs baseline: 2.3372x; 1.0047x over previous
//
#include <hip/hip_runtime.h>
#include <hip/hip_bf16.h>

typedef __attribute__((ext_vector_type(8))) short s16x8;
typedef __attribute__((ext_vector_type(4))) short s16x4;
typedef __attribute__((ext_vector_type(4))) float f32x4;
typedef __attribute__((ext_vector_type(4))) _Float16 f16x4;

#if __has_builtin(__builtin_amdgcn_mfma_f32_16x16x16bf16_1k)
#define PV_USE_BF16 1
#else
#define PV_USE_BF16 0
#endif

#if __has_builtin(__builtin_amdgcn_exp2f)
#define EXP2F(x) __builtin_amdgcn_exp2f(x)
#else
#define EXP2F(x) exp2f(x)
#endif

#define S_LEN 2048
#define EMB   512
#define MROWS 8192   // S*B

__device__ __forceinline__ float bf2f(short x) {
    union { float f; unsigned u; } z; z.u = ((unsigned)(unsigned short)x) << 16; return z.f;
}
// RNE — epilogues only
__device__ __forceinline__ short f2bf(float f) {
    union { float f; unsigned u; } z; z.f = f;
    unsigned r = z.u + 0x7FFF + ((z.u >> 16) & 1);
    return (short)(r >> 16);
}
// fast round-half-away (2 VALU ops) — hot paths
__device__ __forceinline__ short f2bf_fast(float f) {
    union { float f; unsigned u; } z; z.f = f;
    return (short)((z.u + 0x8000u) >> 16);
}
// storage format of V (bf16 normally; f16 when PV falls back to f16 MFMA)
__device__ __forceinline__ short f2v(float f) {
#if PV_USE_BF16
    return f2bf(f);
#else
    union { _Float16 h; short s; } u; u.h = (_Float16)f; return u.s;
#endif
}

// ---------------------------------------------------------------------------
// BT-GEMM mainloop (512 threads = 8 waves, 4x2 wave grid, wave tile 32x64):
// C[128x128] += A[128xK] * B[128xK]^T.  Software-pipelined: next tile's
// global loads issue before computing the current tile from LDS.
// 512 threads -> 2 waves/SIMD even at 1 block/CU (fixes out_proj's zero-TLP).
// ---------------------------------------------------------------------------
template<int AF32, int BF32>
__device__ __forceinline__ void gemm_mainloop(const void* __restrict__ Ag,
                                              const void* __restrict__ Bg,
                                              short* sA, short* sB,
                                              f32x4 acc[2][4], int K)
{
    const int tid  = threadIdx.x;          // 0..511
    const int lane = tid & 63;
    const int wv   = tid >> 6;             // 0..7
    const int l15  = lane & 15, quad = lane >> 4;
    const int wm   = (wv >> 1) * 32, wn = (wv & 1) * 64;

    f32x4 afr[2], bfr[2];   // fp32 staging regs (2 x f32x4 per tile)
    s16x8 ahr, bhr;         // bf16 staging regs (1 x s16x8 per tile)

    auto loadT = [&](const void* G, int kt, f32x4* fr, s16x8& hr, int F32) {
        if (F32) {
#pragma unroll
            for (int p = 0; p < 2; ++p) {
                int c = tid + p * 512;     // 1024 chunks of 4 floats
                fr[p] = *(const f32x4*)((const float*)G + (size_t)(c >> 3) * K + kt + (c & 7) * 4);
            }
        } else {
            hr = *(const s16x8*)((const short*)G + (size_t)(tid >> 2) * K + kt + (tid & 3) * 8);
        }
    };
    auto commitT = [&](short* s, f32x4* fr, s16x8& hr, int F32) {
        if (F32) {
#pragma unroll
            for (int p = 0; p < 2; ++p) {
                int c = tid + p * 512;
                s16x4 o4;
                o4[0] = f2bf_fast(fr[p][0]); o4[1] = f2bf_fast(fr[p][1]);
                o4[2] = f2bf_fast(fr[p][2]); o4[3] = f2bf_fast(fr[p][3]);
                *(s16x4*)(s + c * 4) = o4;
            }
        } else {
            *(s16x8*)(s + tid * 8) = hr;
        }
    };

    // prologue: stage tile 0
    loadT(Ag, 0, afr, ahr, AF32);
    loadT(Bg, 0, bfr, bhr, BF32);
    commitT(sA, afr, ahr, AF32);
    commitT(sB, bfr, bhr, BF32);
    __syncthreads();

    for (int kt = 0; kt < K; kt += 32) {
        const int ktn = (kt + 32 < K) ? kt + 32 : 0;
        loadT(Ag, ktn, afr, ahr, AF32);
        loadT(Bg, ktn, bfr, bhr, BF32);

        s16x8 aF[2], bF[4];
#pragma unroll
        for (int i = 0; i < 2; ++i)
            aF[i] = *(const s16x8*)(sA + (wm + i * 16 + l15) * 32 + quad * 8);
#pragma unroll
        for (int j = 0; j < 4; ++j)
            bF[j] = *(const s16x8*)(sB + (wn + j * 16 + l15) * 32 + quad * 8);
#pragma unroll
        for (int i = 0; i < 2; ++i)
#pragma unroll
            for (int j = 0; j < 4; ++j)
                acc[i][j] = __builtin_amdgcn_mfma_f32_16x16x32_bf16(aF[i], bF[j], acc[i][j], 0, 0, 0);

        __syncthreads();
        commitT(sA, afr, ahr, AF32);
        commitT(sB, bfr, bhr, BF32);
        __syncthreads();
    }
}

// ---------------------------------------------------------------------------
// Kernel 1: fused QKV projection (fp32 in -> bf16 out).
// z=0: q scaled by 0.125*log2(e)  (flash uses exp2 -> native v_exp_f32)
// z=1: k -> (BH,S,HD).  z=2: v written DIRECTLY TRANSPOSED -> vt (BH,HD,S)
// (transpose_v kernel eliminated; stores were scalar-scattered either way).
// Grid (64,4,3): M-tile fastest -> blocks sharing an A-tile are 64 apart
// = same XCD (64 mod 8 == 0) -> A fetched once per XCD, not 4x.
// ---------------------------------------------------------------------------
__global__ __launch_bounds__(512, 4) void qkv_proj(const float* __restrict__ query,
                                                   const float* __restrict__ key,
                                                   const float* __restrict__ value,
                                                   const float* __restrict__ W,
                                                   const float* __restrict__ bias,
                                                   short* __restrict__ q,
                                                   short* __restrict__ k,
                                                   short* __restrict__ vt)
{
    __shared__ __align__(16) short sA[4096], sB[4096];
    const int z = blockIdx.z;
    const float* X  = (z == 0) ? query : (z == 1) ? key : value;
    const float* Wz = W    + (z == 2 ? (size_t)1024 * EMB : 0);
    const float* bz = bias + (z == 2 ? 1024 : 0);
    const float scale = (z == 0) ? 0.125f * 1.44269504f : 1.0f;

    const int blockM = blockIdx.x * 128, blockN = blockIdx.y * 128;

    f32x4 acc[2][4];
#pragma unroll
    for (int i = 0; i < 2; ++i)
#pragma unroll
        for (int j = 0; j < 4; ++j)
            acc[i][j] = (f32x4){0.f, 0.f, 0.f, 0.f};

    gemm_mainloop<1, 1>(X + (size_t)blockM * EMB, Wz + (size_t)blockN * EMB,
                        sA, sB, acc, EMB);

    const int tid = threadIdx.x, lane = tid & 63, wv = tid >> 6;
    const int l15 = lane & 15, quad = lane >> 4;
    const int wm = (wv >> 1) * 32, wn = (wv & 1) * 64;

#pragma unroll
    for (int j = 0; j < 4; ++j) {
        int col = blockN + wn + j * 16 + l15;
        float bval = bz[col];
        int h = col >> 6, hd = col & 63;
#pragma unroll
        for (int i = 0; i < 2; ++i) {
#pragma unroll
            for (int r = 0; r < 4; ++r) {
                int row = blockM + wm + i * 16 + quad * 4 + r;
                int s = row >> 2, b = row & 3;
                float val = (acc[i][j][r] + bval) * scale;
                int bh = b * 8 + h;
                if (z == 2) {
                    vt[((size_t)(bh * 64 + hd)) * 2048 + s] = f2v(val);
                } else {
                    short* dst = (z == 0) ? q : k;
                    dst[((size_t)(bh * 2048 + s)) * 64 + hd] = f2bf(val);
                }
            }
        }
    }
}

// ---------------------------------------------------------------------------
// Kernel 2 (v5.2): flash attention — LDS staging + in-register P^T + exp2.
// Q pre-scaled by log2(e)/8, so p = exp2(s') == softmax weights exactly;
// saves the ln2 multiply inside every exp (16/iter/wave).
// ---------------------------------------------------------------------------
__global__ __launch_bounds__(256, 4) void flash_attn(const short* __restrict__ q,
                                                     const short* __restrict__ k,
                                                     const short* __restrict__ vt,
                                                     short* __restrict__ attn)
{
    __shared__ __align__(16) short sK[64 * 72];   // [key][hd]
    __shared__ __align__(16) short sV[64 * 72];   // [hd][key]
    const int bh = blockIdx.x;            // fast grid dim -> XCD locality
    const int q0 = blockIdx.y * 64;
    const int tid = threadIdx.x, wv = tid >> 6, lane = tid & 63;
    const int l15 = lane & 15, quad = lane >> 4;

    const short* qp = q + ((size_t)(bh * 2048 + q0 + wv * 16 + l15)) * 64 + quad * 8;
    s16x8 qf0 = *(const s16x8*)qp;
    s16x8 qf1 = *(const s16x8*)(qp + 32);

    const short* kg = k  + (size_t)bh * 2048 * 64;   // + (kt+key)*64 + hd
    const short* vg = vt + (size_t)bh * 64 * 2048;   // + hd*2048 + kt + key

    const int r0 = tid >> 3,          c0 = (tid & 7) * 8;
    const int r1 = (tid + 256) >> 3,  c1 = ((tid + 256) & 7) * 8;

#if PV_USE_BF16
    typedef s16x4 pvec;
#else
    typedef f16x4 pvec;
#endif

    f32x4 o[4];
    float lsum = 0.f;
#pragma unroll
    for (int i = 0; i < 4; ++i) o[i] = (f32x4){0.f, 0.f, 0.f, 0.f};

    // ---- prologue: stage tile 0 ----
    s16x8 ka = *(const s16x8*)(kg + (size_t)r0 * 64 + c0);
    s16x8 kb = *(const s16x8*)(kg + (size_t)r1 * 64 + c1);
    s16x8 va = *(const s16x8*)(vg + (size_t)r0 * 2048 + c0);
    s16x8 vb = *(const s16x8*)(vg + (size_t)r1 * 2048 + c1);
    *(s16x8*)(sK + r0 * 72 + c0) = ka;
    *(s16x8*)(sK + r1 * 72 + c1) = kb;
    *(s16x8*)(sV + r0 * 72 + c0) = va;
    *(s16x8*)(sV + r1 * 72 + c1) = vb;
    __syncthreads();

    for (int kt = 0; kt < 2048; kt += 64) {
        const int ktn = (kt + 64) & 2047;   // wraps on last iter (harmless)
        ka = *(const s16x8*)(kg + (size_t)(ktn + r0) * 64 + c0);
        kb = *(const s16x8*)(kg + (size_t)(ktn + r1) * 64 + c1);
        va = *(const s16x8*)(vg + (size_t)r0 * 2048 + ktn + c0);
        vb = *(const s16x8*)(vg + (size_t)r1 * 2048 + ktn + c1);

        // ---- S^T: mfma(A=K, B=Q) -> D[key=quad*4+r][qrow=l15] ----
        f32x4 sc[4];
#pragma unroll
        for (int ct = 0; ct < 4; ++ct) {
            s16x8 kf0 = *(const s16x8*)(sK + (ct * 16 + l15) * 72 + quad * 8);
            s16x8 kf1 = *(const s16x8*)(sK + (ct * 16 + l15) * 72 + quad * 8 + 32);
            f32x4 c = (f32x4){0.f, 0.f, 0.f, 0.f};
            c = __builtin_amdgcn_mfma_f32_16x16x32_bf16(kf0, qf0, c, 0, 0, 0);
            c = __builtin_amdgcn_mfma_f32_16x16x32_bf16(kf1, qf1, c, 0, 0, 0);
            sc[ct] = c;
        }
        // ---- P^T = exp2(S^T) (scores pre-scaled by log2 e); in-lane pack ----
        pvec pf[4];
#pragma unroll
        for (int ct = 0; ct < 4; ++ct)
#pragma unroll
            for (int r = 0; r < 4; ++r) {
                float p = EXP2F(sc[ct][r]);
                lsum += p;
#if PV_USE_BF16
                pf[ct][r] = f2bf_fast(p);
#else
                pf[ct][r] = (_Float16)p;
#endif
            }
        // ---- PV: O[qrow][hd] += P^T-frag x V^T-frag (16x16x16) ----
#pragma unroll
        for (int nt = 0; nt < 4; ++nt)
#pragma unroll
            for (int ct = 0; ct < 4; ++ct) {
                pvec vf = *(const pvec*)(sV + (nt * 16 + l15) * 72 + ct * 16 + quad * 4);
#if PV_USE_BF16
                o[nt] = __builtin_amdgcn_mfma_f32_16x16x16bf16_1k(pf[ct], vf, o[nt], 0, 0, 0);
#else
                o[nt] = __builtin_amdgcn_mfma_f32_16x16x16f16(pf[ct], vf, o[nt], 0, 0, 0);
#endif
            }
        // ---- rotate tile ----
        __syncthreads();
        *(s16x8*)(sK + r0 * 72 + c0) = ka;
        *(s16x8*)(sK + r1 * 72 + c1) = kb;
        *(s16x8*)(sV + r0 * 72 + c0) = va;
        *(s16x8*)(sV + r1 * 72 + c1) = vb;
        __syncthreads();
    }

    // ---- row sums ----
    float s = lsum;
    s += __shfl_xor(s, 16, 64);
    s += __shfl_xor(s, 32, 64);
    float sinv = 1.0f / s;
    float inv[4];
#pragma unroll
    for (int r = 0; r < 4; ++r)
        inv[r] = __shfl(sinv, quad * 20 + r, 64);

    // ---- epilogue ----
    const int b = bh >> 3, h = bh & 7;
#pragma unroll
    for (int r = 0; r < 4; ++r) {
        int srow = q0 + wv * 16 + quad * 4 + r;
#pragma unroll
        for (int nt = 0; nt < 4; ++nt)
            attn[(size_t)(srow * 4 + b) * 512 + h * 64 + nt * 16 + l15] = f2bf(o[nt][r] * inv[r]);
    }
}

// ---------------------------------------------------------------------------
// Kernel 3: output projection. A = attn (bf16 scratch), B = W (fp32), out FP32.
// Grid (64,4): M-tile fastest (same-XCD A-tile sharing). 512 threads ->
// 2 waves/SIMD at 1 block/CU.
// ---------------------------------------------------------------------------
__global__ __launch_bounds__(512, 4) void out_proj(const short* __restrict__ attn,
                                                   const float* __restrict__ W,
                                                   const float* __restrict__ bias,
                                                   float* __restrict__ out)
{
    __shared__ __align__(16) short sA[4096], sB[4096];
    const int blockM = blockIdx.x * 128, blockN = blockIdx.y * 128;

    f32x4 acc[2][4];
#pragma unroll
    for (int i = 0; i < 2; ++i)
#pragma unroll
        for (int j = 0; j < 4; ++j)
            acc[i][j] = (f32x4){0.f, 0.f, 0.f, 0.f};

    gemm_mainloop<0, 1>(attn + (size_t)blockM * EMB, W + (size_t)blockN * EMB,
                        sA, sB, acc, EMB);

    const int tid = threadIdx.x, lane = tid & 63, wv = tid >> 6;
    const int l15 = lane & 15, quad = lane >> 4;
    const int wm = (wv >> 1) * 32, wn = (wv & 1) * 64;

#pragma unroll
    for (int j = 0; j < 4; ++j) {
        int col = blockN + wn + j * 16 + l15;
        float bval = bias[col];
#pragma unroll
        for (int i = 0; i < 2; ++i) {
#pragma unroll
            for (int r = 0; r < 4; ++r) {
                int row = blockM + wm + i * 16 + quad * 4 + r;
                out[(size_t)row * 512 + col] = acc[i][j][r] + bval;
            }
        }
    }
}

// ---------------------------------------------------------------------------
// Dtype contract: inputs FP32, output FP32. Internals bf16 (V possibly f16).
// 3 dispatches (transpose_v fused into qkv_proj's V epilogue):
//   qkv_proj:  fp32 inputs -> bf16 q,k (ws) + V^T directly into d_out
//   flash_attn: q, k, d_out(V^T) -> attn (ws)
//   out_proj:  attn + fp32 W_out -> d_out (fp32 final, overwrites V^T)
// ---------------------------------------------------------------------------
extern "C" void kernel_launch(void* const* d_in, const int* in_sizes, int n_in,
                              void* d_out, int out_size, void* d_ws, size_t ws_size,
                              hipStream_t stream)
{
    const float* query = (const float*)d_in[0];
    const float* key   = (const float*)d_in[1];
    const float* value = (const float*)d_in[2];
    const float* ipw   = (const float*)d_in[3];   // (1536, 512)
    const float* ipb   = (const float*)d_in[4];   // (1536,)
    const float* opw   = (const float*)d_in[5];   // (512, 512)
    const float* opb   = (const float*)d_in[6];   // (512,)
    float* out = (float*)d_out;

    const size_t NELEM = (size_t)MROWS * EMB;     // 4,194,304 elements
    short* q    = (short*)d_ws;
    short* k    = q + NELEM;
    short* attn = k + NELEM;
    short* vt   = (short*)d_out;                  // 16-bit scratch inside fp32 d_out

    qkv_proj  <<<dim3(64, 4, 3), 512, 0, stream>>>(query, key, value, ipw, ipb, q, k, vt);
    flash_attn<<<dim3(32, 32),   256, 0, stream>>>(q, k, vt, attn);
    out_proj  <<<dim3(64, 4),    512, 0, stream>>>(attn, opw, opb, out);
}